// Round 1
// baseline (333.208 us; speedup 1.0000x reference)
//
#include <hip/hip_runtime.h>

// Problem constants (B=4, N=2048 fixed by the reference).
#define NN 2048
#define BB 4
#define PARAM_G 0.125f
#define VIRUS_DEATH 8e-5f

// Workspace layout (floats):
//   [0,      8192)  colsum[b*N+j]  = sum_i F_nm[b,i,j]   (atomics, needs zero-init)
//   [8192,  16384)  rowdotS[b*N+i] = sum_j F_nm[b,i,j]*S[b,j]
//   [16384, 24576)  rowdotI
//   [24576, 32768)  rowdotR
//   [32768, 32772)  fai[b]
//   [32772, 32776)  tau[b]
#define WS_ROWS 8192
#define WS_ROWI 16384
#define WS_ROWR 24576
#define WS_FAI  32768
#define WS_TAU  32772

// ---------------------------------------------------------------------------
// K1: column sums of mob with diagonal zeroed.
// grid (32 row-tiles of 64, 2 col-tiles of 1024, B); block 256.
// Each thread: 4 consecutive columns (float4 loads, coalesced), 64 rows.
__global__ __launch_bounds__(256) void k_colsum(const float* __restrict__ mob,
                                                float* ws) {
    int t  = threadIdx.x;
    int i0 = blockIdx.x * 64;
    int j  = blockIdx.y * 1024 + t * 4;
    int b  = blockIdx.z;
    const float* base = mob + ((size_t)b * NN + i0) * NN + j;
    float4 acc = make_float4(0.f, 0.f, 0.f, 0.f);
    for (int r = 0; r < 64; ++r) {
        float4 v = *(const float4*)(base + (size_t)r * NN);
        unsigned d = (unsigned)((i0 + r) - j);      // diag: i == j+d, d in [0,4)
        if (d < 4u) ((float*)&v)[d] = 0.0f;
        acc.x += v.x; acc.y += v.y; acc.z += v.z; acc.w += v.w;
    }
    atomicAdd(&ws[b * NN + j + 0], acc.x);
    atomicAdd(&ws[b * NN + j + 1], acc.y);
    atomicAdd(&ws[b * NN + j + 2], acc.z);
    atomicAdd(&ws[b * NN + j + 3], acc.w);
}

// ---------------------------------------------------------------------------
// Kt: per-batch scalars. tau[b] = sum_n (S+I+R); fai[b] = sum_j colsum[b,j].
// grid B; block 256 (4 waves).
__global__ __launch_bounds__(256) void k_scalars(const float* __restrict__ SIR,
                                                 float* ws) {
    int b = blockIdx.x;
    int t = threadIdx.x;
    float accT = 0.f, accF = 0.f;
    for (int n = t; n < NN; n += 256) {
        float4 s = *(const float4*)(SIR + ((size_t)b * NN + n) * 4);
        accT += s.x + s.y + s.z;
        accF += ws[b * NN + n];
    }
    for (int off = 32; off; off >>= 1) {
        accT += __shfl_down(accT, off);
        accF += __shfl_down(accF, off);
    }
    __shared__ float red[2][4];
    int w = t >> 6, lane = t & 63;
    if (lane == 0) { red[0][w] = accT; red[1][w] = accF; }
    __syncthreads();
    if (t == 0) {
        ws[WS_TAU + b] = red[0][0] + red[0][1] + red[0][2] + red[0][3];
        ws[WS_FAI + b] = red[1][0] + red[1][1] + red[1][2] + red[1][3];
    }
}

// ---------------------------------------------------------------------------
// K2: the heavy pass. Per row i: write arrive2[b,i,j,{0,1}] = {sps_m, P} and
// accumulate rowdot_X[b,i] = sum_j F[b,i,j] * X[b,j] for X in {S,I,R}.
// grid (N/4, B); block 256 = 4 waves, wave w owns row blockIdx.x*4+w.
// SIR columns staged in LDS once per block.
__global__ __launch_bounds__(256) void k_main(const float* __restrict__ mob,
                                              const float* __restrict__ sps,
                                              const float* __restrict__ SIR,
                                              float* ws,
                                              float* __restrict__ out2) {
    __shared__ __align__(16) float sS[NN];
    __shared__ __align__(16) float sI[NN];
    __shared__ __align__(16) float sR[NN];
    int t = threadIdx.x;
    int b = blockIdx.y;
    for (int j = t; j < NN; j += 256) {
        float4 s = *(const float4*)(SIR + ((size_t)b * NN + j) * 4);
        sS[j] = s.x; sI[j] = s.y; sR[j] = s.z;
    }
    __syncthreads();

    int w = t >> 6, lane = t & 63;
    int i = blockIdx.x * 4 + w;
    float invc = 1.0f / ws[b * NN + i];          // same addr per wave -> broadcast
    size_t rowoff = ((size_t)b * NN + i) * NN;
    const float* mrow = mob + rowoff;
    const float* srow = sps + rowoff;
    float* orow = out2 + rowoff * 2;

    float aS = 0.f, aI = 0.f, aR = 0.f;
    #pragma unroll
    for (int iter = 0; iter < 8; ++iter) {
        int j = iter * 256 + lane * 4;
        float4 mv = *(const float4*)(mrow + j);
        float4 sv = *(const float4*)(srow + j);
        unsigned d = (unsigned)(i - j);          // diag component if d in [0,4)
        if (d < 4u) { ((float*)&mv)[d] = 0.0f; ((float*)&sv)[d] = 0.0f; }
        float4 xS = *(const float4*)&sS[j];
        float4 xI = *(const float4*)&sI[j];
        float4 xR = *(const float4*)&sR[j];
        aS += mv.x * xS.x + mv.y * xS.y + mv.z * xS.z + mv.w * xS.w;
        aI += mv.x * xI.x + mv.y * xI.y + mv.z * xI.z + mv.w * xI.w;
        aR += mv.x * xR.x + mv.y * xR.y + mv.z * xR.z + mv.w * xR.w;
        // interleaved (sps_m, P) pairs: elements j..j+3 -> 8 consecutive floats
        float4 o0 = make_float4(sv.x, mv.x * invc, sv.y, mv.y * invc);
        float4 o1 = make_float4(sv.z, mv.z * invc, sv.w, mv.w * invc);
        *(float4*)(orow + (size_t)j * 2)     = o0;
        *(float4*)(orow + (size_t)j * 2 + 4) = o1;
    }
    for (int off = 32; off; off >>= 1) {
        aS += __shfl_down(aS, off);
        aI += __shfl_down(aI, off);
        aR += __shfl_down(aR, off);
    }
    if (lane == 0) {                              // wave owns the row: no atomics
        ws[WS_ROWS + b * NN + i] = aS;
        ws[WS_ROWI + b * NN + i] = aI;
        ws[WS_ROWR + b * NN + i] = aR;
    }
}

// ---------------------------------------------------------------------------
// K3: per-node epilogue -> Ht_SIR (B,N,6) and arrive1 (B,N,4).
__global__ __launch_bounds__(256) void k_epi(const float* __restrict__ param_b,
                                             const float* __restrict__ contact,
                                             const float* __restrict__ SIR,
                                             const float* __restrict__ nb,
                                             const float* __restrict__ nd,
                                             const float* ws,
                                             float* __restrict__ out0,
                                             float* __restrict__ out1) {
    int g = blockIdx.x * 256 + threadIdx.x;      // b*N + n, total B*N = 8192
    int b = g >> 11;
    int n = g & (NN - 1);
    float4 sir = *(const float4*)(SIR + (size_t)g * 4);
    float S = sir.x, I = sir.y, R = sir.z, Isum = sir.w;
    float pb = param_b[g], ct = contact[g];
    float birth = nb[n], death = nd[n];
    float cs = ws[g];
    float rS = ws[WS_ROWS + g], rI = ws[WS_ROWI + g], rR = ws[WS_ROWR + g];
    float m = ws[WS_FAI + b] / ws[WS_TAU + b];

    float pop   = S + I + R;
    float pbc   = pb * ct;
    float I_new = S / pop * pbc * I;
    float icv   = 1.0f / cs;
    float fS = m * rS * icv, fI = m * rI * icv, fR = m * rR * icv;

    float R_t    = R + PARAM_G * I - death * R - m * R + fR;
    float I_t    = I + I_new - death * I - PARAM_G * I - VIRUS_DEATH * I - m * I + fI;
    float S_t    = S - I_new - death * S + birth * pop - m * S + fS;
    float Isum_t = Isum + I_new;
    float R0     = pbc / (death + PARAM_G + VIRUS_DEATH + m);
    float W      = pbc - death - PARAM_G - VIRUS_DEATH;

    float* o0 = out0 + (size_t)g * 6;            // 24B stride: three float2 stores
    *(float2*)(o0 + 0) = make_float2(R0, I_new);
    *(float2*)(o0 + 2) = make_float2(S_t, I_t);
    *(float2*)(o0 + 4) = make_float2(R_t, Isum_t);
    *(float4*)(out1 + (size_t)g * 4) = make_float4(W, m, I, pop);
}

// ---------------------------------------------------------------------------
extern "C" void kernel_launch(void* const* d_in, const int* in_sizes, int n_in,
                              void* d_out, int out_size, void* d_ws, size_t ws_size,
                              hipStream_t stream) {
    const float* param_b = (const float*)d_in[0];
    const float* contact = (const float*)d_in[1];
    const float* mob     = (const float*)d_in[2];
    const float* SIR     = (const float*)d_in[3];
    const float* sps     = (const float*)d_in[4];
    const float* nb      = (const float*)d_in[5];
    const float* nd      = (const float*)d_in[6];

    float* out  = (float*)d_out;
    float* out0 = out;                            // Ht_SIR   (B,N,6)
    float* out1 = out + (size_t)BB * NN * 6;      // arrive1  (B,N,4)
    float* out2 = out1 + (size_t)BB * NN * 4;     // arrive2  (B,N,N,2)
    float* ws   = (float*)d_ws;

    // zero only the colsum region (atomic accumulation target)
    hipMemsetAsync(ws, 0, (size_t)BB * NN * sizeof(float), stream);

    k_colsum <<<dim3(32, 2, BB),  256, 0, stream>>>(mob, ws);
    k_scalars<<<BB,               256, 0, stream>>>(SIR, ws);
    k_main   <<<dim3(NN / 4, BB), 256, 0, stream>>>(mob, sps, SIR, ws, out2);
    k_epi    <<<(BB * NN) / 256,  256, 0, stream>>>(param_b, contact, SIR, nb, nd,
                                                    ws, out0, out1);
}

// Round 2
// 295.094 us; speedup vs baseline: 1.1292x; 1.1292x over previous
//
#include <hip/hip_runtime.h>

// Problem constants (B=4, N=2048 fixed by the reference).
#define NN 2048
#define BB 4
#define PARAM_G 0.125f
#define VIRUS_DEATH 8e-5f

// Workspace layout (floats):
//   [0,      8192)  colsum[b*N+j]  = sum_i F_nm[b,i,j]   (atomics, zeroed)
//   [8192,  16384)  rowdotS[b*N+i] = sum_j F_nm[b,i,j]*S[b,j]
//   [16384, 24576)  rowdotI
//   [24576, 32768)  rowdotR
//   [32768, 32772)  fai[b]  (atomics, zeroed)
//   [32772, 32776)  tau[b]  (atomics, zeroed)
#define WS_ROWS 8192
#define WS_ROWI 16384
#define WS_ROWR 24576
#define WS_FAI  32768
#define WS_TAU  32772
#define WS_ZERO_FLOATS (WS_TAU + BB)

// ---------------------------------------------------------------------------
// K1: column sums of mob (diag zeroed) + fai[b] partial sums.
// grid (64 row-tiles of 32, 2 col-tiles of 1024, B); block 256; 512 blocks = 2/CU.
// unroll 8 -> 8 independent 16B loads in flight per wave (latency hiding).
__global__ __launch_bounds__(256) void k_colsum(const float* __restrict__ mob,
                                                float* ws) {
    int t  = threadIdx.x;
    int i0 = blockIdx.x * 32;
    int j  = blockIdx.y * 1024 + t * 4;
    int b  = blockIdx.z;
    const float* base = mob + ((size_t)b * NN + i0) * NN + j;
    float4 acc = make_float4(0.f, 0.f, 0.f, 0.f);
    #pragma unroll 8
    for (int r = 0; r < 32; ++r) {
        float4 v = *(const float4*)(base + (size_t)r * NN);
        unsigned d = (unsigned)((i0 + r) - j);      // diag: i == j+d, d in [0,4)
        if (d < 4u) ((float*)&v)[d] = 0.0f;
        acc.x += v.x; acc.y += v.y; acc.z += v.z; acc.w += v.w;
    }
    atomicAdd(&ws[b * NN + j + 0], acc.x);
    atomicAdd(&ws[b * NN + j + 1], acc.y);
    atomicAdd(&ws[b * NN + j + 2], acc.z);
    atomicAdd(&ws[b * NN + j + 3], acc.w);
    // fai[b] = sum of ALL F entries: wave-reduce this thread's partial, 1 atomic/wave
    float s = acc.x + acc.y + acc.z + acc.w;
    for (int off = 32; off; off >>= 1) s += __shfl_down(s, off);
    if ((t & 63) == 0) atomicAdd(&ws[WS_FAI + b], s);
}

// ---------------------------------------------------------------------------
// K2: tau[b] = sum_n (S+I+R). grid 16 (4 slices per batch), block 256.
__global__ __launch_bounds__(256) void k_tau(const float* __restrict__ SIR,
                                             float* ws) {
    int b  = blockIdx.x >> 2;
    int n0 = (blockIdx.x & 3) * 512;
    int t  = threadIdx.x;
    float acc = 0.f;
    #pragma unroll
    for (int k = 0; k < 2; ++k) {
        int n = n0 + k * 256 + t;
        float4 s = *(const float4*)(SIR + ((size_t)b * NN + n) * 4);
        acc += s.x + s.y + s.z;
    }
    for (int off = 32; off; off >>= 1) acc += __shfl_down(acc, off);
    __shared__ float red[4];
    int w = t >> 6;
    if ((t & 63) == 0) red[w] = acc;
    __syncthreads();
    if (t == 0) atomicAdd(&ws[WS_TAU + b], red[0] + red[1] + red[2] + red[3]);
}

// ---------------------------------------------------------------------------
// K3: heavy pass. Per row i: arrive2[b,i,j,{0,1}] = {sps_m, P}; rowdot_X[b,i].
// 2 columns per lane -> float2 loads, ONE float4 store, wave-contiguous 1KB
// per store instruction (full 128B lines; kills the 1.32x write amplification).
// 8 rows per block (2 per wave) amortizes the 32KB SIR->LDS staging.
__global__ __launch_bounds__(256) void k_main(const float* __restrict__ mob,
                                              const float* __restrict__ sps,
                                              const float* __restrict__ SIR,
                                              float* ws,
                                              float* __restrict__ out2) {
    __shared__ __align__(16) float sS[NN];
    __shared__ __align__(16) float sI[NN];
    __shared__ __align__(16) float sR[NN];
    int t = threadIdx.x;
    int b = blockIdx.y;
    for (int j = t; j < NN; j += 256) {
        float4 s = *(const float4*)(SIR + ((size_t)b * NN + j) * 4);
        sS[j] = s.x; sI[j] = s.y; sR[j] = s.z;
    }
    __syncthreads();

    int w = t >> 6, lane = t & 63;
    int i0 = blockIdx.x * 8;
    #pragma unroll
    for (int k = 0; k < 2; ++k) {
        int i = i0 + w + 4 * k;
        float invc = 1.0f / ws[b * NN + i];        // wave-uniform -> s-load
        size_t rowoff = ((size_t)b * NN + i) * NN;
        const float* mrow = mob + rowoff;
        const float* srow = sps + rowoff;
        float* orow = out2 + rowoff * 2;
        float aS = 0.f, aI = 0.f, aR = 0.f;
        #pragma unroll 4
        for (int iter = 0; iter < 16; ++iter) {
            int j2 = iter * 128 + lane * 2;        // this lane's column pair
            float2 mv = *(const float2*)(mrow + j2);
            float2 sv = *(const float2*)(srow + j2);
            unsigned d = (unsigned)(i - j2);       // diag if d in {0,1}
            if (d == 0u)      { mv.x = 0.f; sv.x = 0.f; }
            else if (d == 1u) { mv.y = 0.f; sv.y = 0.f; }
            float2 xS = *(const float2*)&sS[j2];
            float2 xI = *(const float2*)&sI[j2];
            float2 xR = *(const float2*)&sR[j2];
            aS += mv.x * xS.x + mv.y * xS.y;
            aI += mv.x * xI.x + mv.y * xI.y;
            aR += mv.x * xR.x + mv.y * xR.y;
            *(float4*)(orow + (size_t)j2 * 2) =
                make_float4(sv.x, mv.x * invc, sv.y, mv.y * invc);
        }
        for (int off = 32; off; off >>= 1) {
            aS += __shfl_down(aS, off);
            aI += __shfl_down(aI, off);
            aR += __shfl_down(aR, off);
        }
        if (lane == 0) {                            // wave owns the row: no atomics
            ws[WS_ROWS + b * NN + i] = aS;
            ws[WS_ROWI + b * NN + i] = aI;
            ws[WS_ROWR + b * NN + i] = aR;
        }
    }
}

// ---------------------------------------------------------------------------
// K4: per-node epilogue -> Ht_SIR (B,N,6) and arrive1 (B,N,4).
__global__ __launch_bounds__(256) void k_epi(const float* __restrict__ param_b,
                                             const float* __restrict__ contact,
                                             const float* __restrict__ SIR,
                                             const float* __restrict__ nb,
                                             const float* __restrict__ nd,
                                             const float* ws,
                                             float* __restrict__ out0,
                                             float* __restrict__ out1) {
    int g = blockIdx.x * 256 + threadIdx.x;        // b*N + n, total B*N = 8192
    int b = g >> 11;
    int n = g & (NN - 1);
    float4 sir = *(const float4*)(SIR + (size_t)g * 4);
    float S = sir.x, I = sir.y, R = sir.z, Isum = sir.w;
    float pb = param_b[g], ct = contact[g];
    float birth = nb[n], death = nd[n];
    float cs = ws[g];
    float rS = ws[WS_ROWS + g], rI = ws[WS_ROWI + g], rR = ws[WS_ROWR + g];
    float m = ws[WS_FAI + b] / ws[WS_TAU + b];

    float pop   = S + I + R;
    float pbc   = pb * ct;
    float I_new = S / pop * pbc * I;
    float icv   = 1.0f / cs;
    float fS = m * rS * icv, fI = m * rI * icv, fR = m * rR * icv;

    float R_t    = R + PARAM_G * I - death * R - m * R + fR;
    float I_t    = I + I_new - death * I - PARAM_G * I - VIRUS_DEATH * I - m * I + fI;
    float S_t    = S - I_new - death * S + birth * pop - m * S + fS;
    float Isum_t = Isum + I_new;
    float R0     = pbc / (death + PARAM_G + VIRUS_DEATH + m);
    float W      = pbc - death - PARAM_G - VIRUS_DEATH;

    float* o0 = out0 + (size_t)g * 6;
    *(float2*)(o0 + 0) = make_float2(R0, I_new);
    *(float2*)(o0 + 2) = make_float2(S_t, I_t);
    *(float2*)(o0 + 4) = make_float2(R_t, Isum_t);
    *(float4*)(out1 + (size_t)g * 4) = make_float4(W, m, I, pop);
}

// ---------------------------------------------------------------------------
extern "C" void kernel_launch(void* const* d_in, const int* in_sizes, int n_in,
                              void* d_out, int out_size, void* d_ws, size_t ws_size,
                              hipStream_t stream) {
    const float* param_b = (const float*)d_in[0];
    const float* contact = (const float*)d_in[1];
    const float* mob     = (const float*)d_in[2];
    const float* SIR     = (const float*)d_in[3];
    const float* sps     = (const float*)d_in[4];
    const float* nb      = (const float*)d_in[5];
    const float* nd      = (const float*)d_in[6];

    float* out  = (float*)d_out;
    float* out0 = out;                            // Ht_SIR   (B,N,6)
    float* out1 = out + (size_t)BB * NN * 6;      // arrive1  (B,N,4)
    float* out2 = out1 + (size_t)BB * NN * 4;     // arrive2  (B,N,N,2)
    float* ws   = (float*)d_ws;

    hipMemsetAsync(ws, 0, (size_t)WS_ZERO_FLOATS * sizeof(float), stream);

    k_colsum<<<dim3(64, 2, BB),  256, 0, stream>>>(mob, ws);
    k_tau   <<<16,               256, 0, stream>>>(SIR, ws);
    k_main  <<<dim3(NN / 8, BB), 256, 0, stream>>>(mob, sps, SIR, ws, out2);
    k_epi   <<<(BB * NN) / 256,  256, 0, stream>>>(param_b, contact, SIR, nb, nd,
                                                   ws, out0, out1);
}